// Round 9
// baseline (132.757 us; speedup 1.0000x reference)
//
#include <hip/hip_runtime.h>

// Problem dims (fixed by setup_inputs): x [B,N,C], adapter dim D, patch grid HxH
#define B_  64
#define N_  1024
#define H_  32
#define C_  768
#define D_  8
#define WS_ 772   // padded weight stride: bank(772*d+c) = (4d+c)%32 -> d-spans disjoint

__device__ __forceinline__ float qgelu(float v) {
    return v / (1.0f + __expf(-1.702f * v));
}

// ---------------- Kernel 1: x_down = quick_gelu(x @ Wd + bd) ----------------
// v9 = v8 with the coverage bug fixed (48 chunks, not 12).
// One thread per output element (row, d). Thread dots its full 768-float row
// against weight row d broadcast from LDS (stride 772: the 8 d-spans start
// 4 banks apart; each b128 spans 4 banks -> all 32 banks hit exactly once,
// conflict-free, 8-lane same-address broadcast free). x reads: 8 lanes share
// each address -> 128 B unique per wave-instr, coalesced. 3-deep rotating
// chunk pipeline (named arrays = compile-time indexed): ~2 chunks (8 loads,
// 1 KB unique) in flight per wave at all times; 16 waves/CU at (256,4).
__global__ __launch_bounds__(256, 4) void k_down(
    const float* __restrict__ x, const float* __restrict__ Wd,
    const float* __restrict__ bd, float* __restrict__ t1)
{
    __shared__ float sW[D_ * WS_];   // transposed+padded: sW[d*WS_ + c]
    for (int i = threadIdx.x; i < D_ * C_; i += 256) {
        const int c = i >> 3, d = i & 7;
        sW[d * WS_ + c] = Wd[i];     // Wd is [C][D] row-major
    }
    __syncthreads();

    const int tid = blockIdx.x * 256 + threadIdx.x;
    const int row = tid >> 3;        // 0..65535
    const int d   = tid & 7;
    const float4* xp = (const float4*)(x + (size_t)row * C_);
    const float*  wr = &sW[d * WS_];

    float acc = 0.0f;
    float4 A[4], B[4], C[4];

    // load chunk K (16 floats = 4 float4) of this thread's row
#define LD(BUF, K)                                                           \
    { _Pragma("unroll")                                                      \
      for (int j = 0; j < 4; ++j) BUF[j] = xp[(K) * 4 + j]; }

    // accumulate chunk K against broadcast weights (4 conflict-free b128s)
#define CH(BUF, K)                                                           \
    { const float4* wk = (const float4*)(wr + (K) * 16);                     \
      _Pragma("unroll")                                                      \
      for (int j = 0; j < 4; ++j) {                                          \
          const float4 wv = wk[j];                                           \
          acc += BUF[j].x * wv.x + BUF[j].y * wv.y                           \
               + BUF[j].z * wv.z + BUF[j].w * wv.w;                          \
      } }

    LD(A, 0)
    LD(B, 1)
    LD(C, 2)
#pragma unroll 1
    for (int k = 0; k < 45; k += 3) {      // k = 0,3,...,42
        CH(A, k)     LD(A, k + 3)
        CH(B, k + 1) LD(B, k + 4)
        CH(C, k + 2) LD(C, k + 5)
    }
    CH(A, 45)
    CH(B, 46)
    CH(C, 47)
#undef LD
#undef CH

    // store: out idx = row*8 + d = tid -> perfectly coalesced
    t1[tid] = qgelu(acc + bd[d]);
}

// ------------- Kernel 2: t2 = quick_gelu(conv3x3(t1) + bc) ------------------
// (unchanged)
__global__ __launch_bounds__(256, 4) void k_conv(
    const float* __restrict__ t1, const float* __restrict__ Wc,
    const float* __restrict__ bc, float* __restrict__ t2)
{
    __shared__ float sIn[10 * H_ * D_];     // 10 rows x 32 cols x 8 ch = 10 KB
    __shared__ float sWc[9 * D_ * D_];
    __shared__ float sbc[D_];

    const int img   = blockIdx.x >> 2;
    const int strip = blockIdx.x & 3;
    const int h0    = strip * 8;
    const float* in = t1 + (size_t)img * N_ * D_;

#pragma unroll
    for (int j = 0; j < 10; ++j) {
        const int i  = threadIdx.x + j * 256;
        const int lr = i >> 8;
        const int rem = i & 255;
        const int g  = h0 - 1 + lr;
        sIn[i] = (g >= 0 && g < H_) ? in[(size_t)g * H_ * D_ + rem] : 0.0f;
    }
    for (int i = threadIdx.x; i < 9 * D_ * D_; i += 256) sWc[i] = Wc[i];
    if (threadIdx.x < D_) sbc[threadIdx.x] = bc[threadIdx.x];
    __syncthreads();

    const int lh = threadIdx.x >> 5;
    const int w  = threadIdx.x & 31;
    float acc[D_];
#pragma unroll
    for (int co = 0; co < D_; ++co) acc[co] = sbc[co];

#pragma unroll
    for (int kh = 0; kh < 3; ++kh) {
        const int lrow = lh + kh;
#pragma unroll
        for (int kw = 0; kw < 3; ++kw) {
            const int ww = w + kw - 1;
            if (ww < 0 || ww >= H_) continue;
            const float* ip = &sIn[(lrow * H_ + ww) * D_];
            const float* wp = &sWc[(kh * 3 + kw) * D_ * D_];
#pragma unroll
            for (int ci = 0; ci < D_; ++ci) {
                const float iv = ip[ci];
#pragma unroll
                for (int co = 0; co < D_; ++co)
                    acc[co] += iv * wp[ci * D_ + co];
            }
        }
    }
    float4 o0, o1;
    o0.x = qgelu(acc[0]); o0.y = qgelu(acc[1]);
    o0.z = qgelu(acc[2]); o0.w = qgelu(acc[3]);
    o1.x = qgelu(acc[4]); o1.y = qgelu(acc[5]);
    o1.z = qgelu(acc[6]); o1.w = qgelu(acc[7]);
    float* tp = t2 + ((size_t)img * N_ + (size_t)(h0 + lh) * H_ + w) * D_;
    *(float4*)tp       = o0;
    *(float4*)(tp + 4) = o1;
}

// ---------------- Kernel 3: out = t2 @ Wu + bu ------------------------------
// (unchanged: register-weight, LDS-free, write-bound)
__global__ __launch_bounds__(256, 3) void k_up(
    const float* __restrict__ t2, const float* __restrict__ Wu,
    const float* __restrict__ bu, float* __restrict__ out, int nrows)
{
    const int wid  = threadIdx.x >> 6;
    const int lane = threadIdx.x & 63;

    float4 w[3][D_];
    float4 bias[3];
#pragma unroll
    for (int j = 0; j < 3; ++j) {
        bias[j] = *(const float4*)&bu[(lane + j * 64) * 4];
#pragma unroll
        for (int d = 0; d < D_; ++d)
            w[j][d] = *(const float4*)&Wu[d * C_ + (lane + j * 64) * 4];
    }

    const int stride = gridDim.x * 4;
    for (int row = blockIdx.x * 4 + wid; row < nrows; row += stride) {
        const float4* rp = (const float4*)(t2 + (size_t)row * D_);
        const float4 ra = rp[0];
        const float4 rb = rp[1];
        const float rv[D_] = { ra.x, ra.y, ra.z, ra.w, rb.x, rb.y, rb.z, rb.w };

#pragma unroll
        for (int j = 0; j < 3; ++j) {
            float4 o = bias[j];
#pragma unroll
            for (int d = 0; d < D_; ++d) {
                o.x += rv[d] * w[j][d].x;
                o.y += rv[d] * w[j][d].y;
                o.z += rv[d] * w[j][d].z;
                o.w += rv[d] * w[j][d].w;
            }
            *(float4*)&out[(size_t)row * C_ + (size_t)(lane + j * 64) * 4] = o;
        }
    }
}

extern "C" void kernel_launch(void* const* d_in, const int* in_sizes, int n_in,
                              void* d_out, int out_size, void* d_ws, size_t ws_size,
                              hipStream_t stream) {
    const float* x  = (const float*)d_in[0];
    const float* Wd = (const float*)d_in[1];
    const float* bd = (const float*)d_in[2];
    const float* Wc = (const float*)d_in[3];
    const float* bc = (const float*)d_in[4];
    const float* Wu = (const float*)d_in[5];
    const float* bu = (const float*)d_in[6];
    float* out = (float*)d_out;

    const int nrows = B_ * N_;                  // 65536
    float* t1 = (float*)d_ws;                   // [nrows][D_]  (2 MB)
    float* t2 = t1 + (size_t)nrows * D_;        // [nrows][D_]  (2 MB)

    // K1 v9: one thread per output element; 2048 blocks.
    k_down<<<(nrows * D_) / 256, 256, 0, stream>>>(x, Wd, bd, t1);
    // K2: 4 blocks per image (unchanged)
    k_conv<<<B_ * 4, 256, 0, stream>>>(t1, Wc, bc, t2);
    // K3: register-weight, LDS-free (unchanged)
    k_up<<<768, 256, 0, stream>>>(t2, Wu, bu, out, nrows);
}